// Round 7
// baseline (225.628 us; speedup 1.0000x reference)
//
#include <hip/hip_runtime.h>
#include <math.h>

#define DD 33
#define TT 49
#define HH 64
#define NB 33
#define NT 256

// ws layout (float offsets)
#define O_WIHT  0        // 33*192 wih^T   [k*192+j]
#define O_WHHT  6336     // 64*192 whh^T   [k*192+j]
#define O_GH    18624    // 49*64  gamma_h[t][i]
#define O_GS    21760    // 49*64  gamma_st[t][i]
#define O_WT0   24896    // 33*64   wu0^T . whr1
#define O_WT1   27008    // 33*128  wu1^T . whr1
#define O_WTG   31232    // 33*192  wu^T  . whr1
#define O_CU    37568    // 33*4    whr1 . {wu0b,wu1b,wub,0}
#define O_R     37700    // 49*66   published r1(33), r2(33)
#define O_PF    40936    // (TT+1)*64 u64 packed {tag,xc}; 512B stride/step
#define O_FLG   47336    // (TT+1) u32 aggregated ready tags
#define PREP_N  37700

#define SC_AGENT __HIP_MEMORY_SCOPE_AGENT

__device__ __forceinline__ float sigm(float x) {
  return 1.f / (1.f + __expf(-x));
}
__device__ __forceinline__ float ftanh(float x) {
  x = fminf(fmaxf(x, -15.f), 15.f);
  float e = __expf(2.f * x);
  return (e - 1.f) / (e + 1.f);
}

__device__ __forceinline__ float rsum64(float v) {
#pragma unroll
  for (int o = 32; o > 0; o >>= 1) v += __shfl_xor(v, o, 64);
  return v;
}
__device__ __forceinline__ float rmax64(float v) {
#pragma unroll
  for (int o = 32; o > 0; o >>= 1) v = fmaxf(v, __shfl_xor(v, o, 64));
  return v;
}

extern "C" __global__ void gmgru_prep(
    const float* __restrict__ data, const float* __restrict__ gh_w,
    const float* __restrict__ gh_b, const float* __restrict__ gst_w,
    const float* __restrict__ gst_b, const float* __restrict__ wih,
    const float* __restrict__ whh, const float* __restrict__ wu0,
    const float* __restrict__ wu0b, const float* __restrict__ wu1,
    const float* __restrict__ wu1b, const float* __restrict__ wu,
    const float* __restrict__ wub, const float* __restrict__ wh_w,
    float* __restrict__ ws) {
  int idx = blockIdx.x * blockDim.x + threadIdx.x;
  if (idx < 6336) {                        // wihT[k*192+j] = wih[j*33+k]
    int k = idx / 192, j = idx % 192;
    ws[O_WIHT + idx] = wih[j * DD + k];
  } else if (idx < 18624) {                // whhT[k*192+j] = whh[j*64+k]
    int r = idx - 6336, k = r / 192, j = r % 192;
    ws[O_WHHT + r] = whh[j * HH + k];
  } else if (idx < 21760) {                // gamma_h[t][i]
    int r = idx - 18624, t = r / 64, i = r % 64;
    float s = gh_b[i];
    for (int d2 = 0; d2 < DD; ++d2)
      s += data[2 * DD * TT + d2 * TT + t] * gh_w[i * DD + d2];
    ws[O_GH + r] = expf(-fmaxf(s, 0.f));
  } else if (idx < 24896) {                // gamma_st[t][i]
    int r = idx - 21760, t = r / 64, i = r % 64;
    float s = gst_b[i];
    for (int d2 = 0; d2 < DD; ++d2)
      s += data[2 * DD * TT + d2 * TT + t] * gst_w[i * DD + d2];
    ws[O_GS + r] = expf(-fmaxf(s, 0.f));
  } else if (idx < 27008) {                // wt0[dd][k] = sum_q wu0[q][k]*whr1[q]
    int r = idx - 24896, dd = r / 64, k = r % 64;
    float s = 0.f;
    for (int q = 0; q < 64; ++q) s += wu0[q * 64 + k] * wh_w[dd * 128 + 64 + q];
    ws[O_WT0 + r] = s;
  } else if (idx < 31232) {                // wt1[dd][k]
    int r = idx - 27008, dd = r / 128, k = r % 128;
    float s = 0.f;
    for (int q = 0; q < 64; ++q) s += wu1[q * 128 + k] * wh_w[dd * 128 + 64 + q];
    ws[O_WT1 + r] = s;
  } else if (idx < 37568) {                // wtg[dd][k]
    int r = idx - 31232, dd = r / 192, k = r % 192;
    float s = 0.f;
    for (int q = 0; q < 64; ++q) s += wu[q * 192 + k] * wh_w[dd * 128 + 64 + q];
    ws[O_WTG + r] = s;
  } else if (idx < PREP_N) {               // cu[dd][v] = whr1 . bias_v
    int r = idx - 37568, dd = r / 4, v = r % 4;
    float s = 0.f;
    if (v < 3) {
      const float* bp = (v == 0) ? wu0b : (v == 1) ? wu1b : wub;
      for (int q = 0; q < 64; ++q) s += bp[q] * wh_w[dd * 128 + 64 + q];
    }
    ws[O_CU + r] = s;
  }
}

extern "C" __global__ void __launch_bounds__(NT, 1)
gmgru_main(const float* __restrict__ data, const float* __restrict__ h0,
           const float* __restrict__ H0, const float* __restrict__ bih,
           const float* __restrict__ bhh, const float* __restrict__ wh_w,
           const float* __restrict__ wh_b, const float* __restrict__ xst_w,
           const float* __restrict__ xst_b, const float* __restrict__ wrg_w,
           const float* __restrict__ wrs, const float* __restrict__ tWz,
           const float* __restrict__ tUzx, const float* __restrict__ tUzh,
           const float* __restrict__ tWr, const float* __restrict__ tUrx,
           const float* __restrict__ tUrh, const float* __restrict__ tWh,
           const float* __restrict__ tUhx, const float* __restrict__ tUhh,
           const float* __restrict__ tbz, const float* __restrict__ tbr,
           const float* __restrict__ tbh, float* __restrict__ ws,
           unsigned long long* __restrict__ pf, unsigned* __restrict__ flg,
           float* __restrict__ out) {
  __shared__ __attribute__((aligned(16))) float ubuf[3][4096];  // 48 KB
  __shared__ float whhT_l[12288];                               // 48 KB
  __shared__ float wihT_l[6336];                                // 25 KB
  __shared__ float partW[3][4][HH], partU[3][4][HH];            // 6 KB
  __shared__ float hpreL[HH], hnewL[HH], ghLDS[3 * HH];
  __shared__ float gpre[2][HH];
  __shared__ float xrow[TT], mrow[TT];
  __shared__ float xcddL;

  const int tid = threadIdx.x;
  const int dd = blockIdx.x;
  const int wid = tid >> 6;
  const int lane = tid & 63;

  // ---- one-time staging ----
  {
    const float* usrc[3] = {tUzh, tUrh, tUhh};
#pragma unroll 1
    for (int m = 0; m < 3; ++m) {
      const float* s = usrc[m] + dd * 4096;
#pragma unroll
      for (int c = 0; c < 4; ++c) {
        int f = tid * 16 + c * 4;  // source flat idx (i*64+k)
        float4 v = *reinterpret_cast<const float4*>(s + f);
        int i = f >> 6, k = f & 63;
        *reinterpret_cast<float4*>(&ubuf[m][(k >> 2) * 256 + i * 4]) = v;
      }
    }
  }
  for (int i = tid; i < 12288; i += NT) whhT_l[i] = ws[O_WHHT + i];
  for (int i = tid; i < 6336; i += NT) wihT_l[i] = ws[O_WIHT + i];
  if (tid < HH) {
    gpre[0][tid] = ws[O_GH + tid];
    gpre[1][tid] = ws[O_GS + tid];
  }
  if (tid < TT) {
    xrow[tid] = data[dd * TT + tid];
    mrow[tid] = data[DD * TT + dd * TT + tid];
  }
  // per-lane registers
  const float bih_r = bih[lane];
  const float bih_z = bih[64 + lane];
  const float bih_n = bih[128 + lane];
  const float bhh_r = (tid < 192) ? bhh[tid] : 0.f;
  const float ux0 = tUzx[dd * HH + lane];
  const float ux1 = tUrx[dd * HH + lane];
  const float ux2 = tUhx[dd * HH + lane];
  const float tb0 = tbz[lane];
  const float tb1 = tbr[lane];
  const float tb2 = tbh[lane];
  const float xstw_r = xst_w[lane];
  const float wrg_r = wrg_w[dd * HH + lane];
  const float wrs_r = wrs[lane];
  const float whr0_r = wh_w[dd * 128 + lane];
  const float wtg0_r = ws[O_WTG + dd * 192 + lane];
  const float wtg1_r = ws[O_WTG + dd * 192 + 64 + lane];
  const float wtg2_r = ws[O_WTG + dd * 192 + 128 + lane];
  const float wt0_r = ws[O_WT0 + dd * 64 + lane];
  const float wt1a_r = ws[O_WT1 + dd * 128 + lane];
  const float wt1b_r = ws[O_WT1 + dd * 128 + 64 + lane];
  const float cu0_r = ws[O_CU + dd * 4 + 0];
  const float cu1_r = ws[O_CU + dd * 4 + 1];
  const float cu2_r = ws[O_CU + dd * 4 + 2];
  const float whb_r = wh_b[dd];
  const float xstb_r = xst_b[0];
  const float h0s_r = h0[lane];
  float hprev = h0s_r;
  float Hrow = H0[dd * HH + lane];
  __syncthreads();

  // ---- prologue: x_st(0); publish slot[0] = {tag 1, xc(0)} ----
  float xst_cur = rsum64(Hrow * xstw_r) + xstb_r;
  if (wid == 0 && lane == 0) {
    float xc0 = mrow[0] * xrow[0] + (1.f - mrow[0]) * xst_cur;
    unsigned long long pk0 =
        (1ULL << 32) | (unsigned long long)__float_as_uint(xc0);
    __hip_atomic_store(&pf[dd], pk0, __ATOMIC_RELAXED, SC_AGENT);
  }
  // wave1 rings (registers)
  float xg_m1 = 0.f, xg_m2 = 0.f, xs_m1 = 0.f, xs_m2 = 0.f;
  float h1 = 0.f, h2 = 0.f, h3 = 0.f;

  for (int t = 0; t < TT; ++t) {
    __syncthreads();  // S0: prev wave3 gpre write -> this-step reads
    float hpre_r = gpre[0][lane] * hprev;
    float Hdec_r = gpre[1][lane] * Hrow;
    if (wid == 0) hpreL[lane] = hpre_r;
    __syncthreads();  // S1

    // ---- pre-phase (off critical path): W-half from global + gh_ GEMV ----
    {
      float pw0 = 0.f, pw1 = 0.f, pw2 = 0.f;
      const int base = dd * 4096 + lane * 64 + wid * 16;
#pragma unroll
      for (int g = 0; g < 4; ++g) {
        float4 a = *reinterpret_cast<const float4*>(tWz + base + g * 4);
        float4 bb = *reinterpret_cast<const float4*>(tWr + base + g * 4);
        float4 c = *reinterpret_cast<const float4*>(tWh + base + g * 4);
        float v0 = __shfl(Hdec_r, wid * 16 + g * 4 + 0, 64);
        float v1 = __shfl(Hdec_r, wid * 16 + g * 4 + 1, 64);
        float v2 = __shfl(Hdec_r, wid * 16 + g * 4 + 2, 64);
        float v3 = __shfl(Hdec_r, wid * 16 + g * 4 + 3, 64);
        pw0 += a.x * v0 + a.y * v1 + a.z * v2 + a.w * v3;
        pw1 += bb.x * v0 + bb.y * v1 + bb.z * v2 + bb.w * v3;
        pw2 += c.x * v0 + c.y * v1 + c.z * v2 + c.w * v3;
      }
      partW[0][wid][lane] = pw0;
      partW[1][wid][lane] = pw1;
      partW[2][wid][lane] = pw2;
    }
    if (tid < 3 * HH) {
      float a0 = 0.f, a1 = 0.f, a2 = 0.f, a3 = 0.f;
#pragma unroll
      for (int k = 0; k < HH; k += 4) {
        a0 += whhT_l[(k + 0) * 192 + tid] * hpreL[k + 0];
        a1 += whhT_l[(k + 1) * 192 + tid] * hpreL[k + 1];
        a2 += whhT_l[(k + 2) * 192 + tid] * hpreL[k + 2];
        a3 += whhT_l[(k + 3) * 192 + tid] * hpreL[k + 3];
      }
      ghLDS[tid] = bhh_r + ((a0 + a1) + (a2 + a3));
    }
    __syncthreads();  // S_b: ghLDS/partW ready before wave0's post-spin reads

    // ---- discovery: block0.wave0 aggregates; others poll single flag ----
    float hn = 0.f;
    if (wid == 0) {
      const unsigned tagv = (unsigned)(t + 1);
      float xcv;
      if (dd == 0) {
        unsigned long long pk;
        for (;;) {
          pk = (lane < NB)
                   ? __hip_atomic_load(&pf[(size_t)t * 64 + lane],
                                       __ATOMIC_RELAXED, SC_AGENT)
                   : (((unsigned long long)tagv) << 32);
          if (__all((int)((unsigned)(pk >> 32) == tagv))) break;
        }
        if (lane == 0)
          __hip_atomic_store(&flg[t], tagv, __ATOMIC_RELAXED, SC_AGENT);
        xcv = __uint_as_float((unsigned)(pk & 0xFFFFFFFFull));
      } else {
        for (;;) {
          unsigned fv = (lane == 0) ? __hip_atomic_load(&flg[t],
                                                        __ATOMIC_RELAXED,
                                                        SC_AGENT)
                                    : 0u;
          fv = (unsigned)__shfl((int)fv, 0, 64);
          if (fv == tagv) break;
          __builtin_amdgcn_s_sleep(1);
        }
        unsigned long long pk =
            (lane < NB) ? __hip_atomic_load(&pf[(size_t)t * 64 + lane],
                                            __ATOMIC_RELAXED, SC_AGENT)
                        : 0ULL;
        xcv = __uint_as_float((unsigned)(pk & 0xFFFFFFFFull));
      }
      asm volatile("" ::: "memory");
      float gr = bih_r, gz = bih_z, gn = bih_n;
#pragma unroll
      for (int k = 0; k < DD; ++k) {
        float xk = __shfl(xcv, k, 64);
        gr += wihT_l[k * 192 + lane] * xk;
        gz += wihT_l[k * 192 + 64 + lane] * xk;
        gn += wihT_l[k * 192 + 128 + lane] * xk;
      }
      float rg = sigm(gr + ghLDS[lane]);
      float zg = sigm(gz + ghLDS[64 + lane]);
      float ng = ftanh(gn + rg * ghLDS[128 + lane]);
      hn = (1.f - zg) * ng + zg * hpre_r;
      hnewL[lane] = hn;
      float xcd = __shfl(xcv, dd, 64);
      if (lane == 0) xcddL = xcd;
    }
    __syncthreads();  // S3

    // ---- U-half partials from LDS (all waves) ----
    {
      float hv[16];
#pragma unroll
      for (int j = 0; j < 16; ++j) hv[j] = hnewL[wid * 16 + j];
      float pu0 = 0.f, pu1 = 0.f, pu2 = 0.f;
#pragma unroll
      for (int g = 0; g < 4; ++g) {
        const int kg = (wid * 4 + g) * 256 + lane * 4;
        float4 a = *reinterpret_cast<const float4*>(&ubuf[0][kg]);
        float4 bb = *reinterpret_cast<const float4*>(&ubuf[1][kg]);
        float4 c = *reinterpret_cast<const float4*>(&ubuf[2][kg]);
        const float v0 = hv[g * 4 + 0], v1 = hv[g * 4 + 1];
        const float v2 = hv[g * 4 + 2], v3 = hv[g * 4 + 3];
        pu0 += a.x * v0 + a.y * v1 + a.z * v2 + a.w * v3;
        pu1 += bb.x * v0 + bb.y * v1 + bb.z * v2 + bb.w * v3;
        pu2 += c.x * v0 + c.y * v1 + c.z * v2 + c.w * v3;
      }
      partU[0][wid][lane] = pu0;
      partU[1][wid][lane] = pu1;
      partU[2][wid][lane] = pu2;
    }
    __syncthreads();  // S4

    // wave1: issue r(t-2) gather early (hides under combine)
    float r1v = -INFINITY, r2v = -INFINITY;
    if (wid == 1 && t >= 2 && lane < DD) {
      r1v = __hip_atomic_load(&ws[O_R + (t - 2) * 66 + lane], __ATOMIC_RELAXED,
                              SC_AGENT);
      r2v = __hip_atomic_load(&ws[O_R + (t - 2) * 66 + 33 + lane],
                              __ATOMIC_RELAXED, SC_AGENT);
    }

    // ---- combine (redundant per wave) -> H_t ----
    float sz = partW[0][0][lane] + partW[0][1][lane] + partW[0][2][lane] +
               partW[0][3][lane] + partU[0][0][lane] + partU[0][1][lane] +
               partU[0][2][lane] + partU[0][3][lane];
    float sr = partW[1][0][lane] + partW[1][1][lane] + partW[1][2][lane] +
               partW[1][3][lane] + partU[1][0][lane] + partU[1][1][lane] +
               partU[1][2][lane] + partU[1][3][lane];
    float swh = partW[2][0][lane] + partW[2][1][lane] + partW[2][2][lane] +
                partW[2][3][lane];
    float suh = partU[2][0][lane] + partU[2][1][lane] + partU[2][2][lane] +
                partU[2][3][lane];
    float xc = xcddL;
    float z2 = sigm(sz + ux0 * xc + tb0);
    float r2g = sigm(sr + ux1 * xc + tb1);
    float hh = ftanh(r2g * swh + ux2 * xc + suh + tb2);
    float Hn = z2 * Hdec_r + (1.f - z2) * hh;
    if (wid != 0) hn = hnewL[lane];

    // ---- role split ----
    if (wid == 0) {
      float xsn = rsum64(xstw_r * Hn);
      if (lane == 0 && t < TT - 1) {
        float xstv = xsn + xstb_r;
        float xcn = mrow[t + 1] * xrow[t + 1] + (1.f - mrow[t + 1]) * xstv;
        unsigned long long pkn =
            (((unsigned long long)(unsigned)(t + 2)) << 32) |
            (unsigned long long)__float_as_uint(xcn);
        __hip_atomic_store(&pf[(size_t)(t + 1) * 64 + dd], pkn,
                           __ATOMIC_RELAXED, SC_AGENT);
      }
    } else if (wid == 1) {
      if (t >= 2) {
        float m1 = rmax64(r1v), m2 = rmax64(r2v);
        float e1 = (lane < DD) ? __expf(r1v - m1) : 0.f;
        float e2 = (lane < DD) ? __expf(r2v - m2) : 0.f;
        float s1 = rsum64(e1), s2 = rsum64(e2);
        float r1o = __shfl(r1v, dd, 64);
        float r2o = __shfl(r2v, dd, 64);
        if (lane == 0) {
          float a1 = __expf(r1o - m1) / s1;
          float a2 = __expf(r2o - m2) / s2;
          out[TT * DD * HH + dd * TT + (t - 2)] = a1 * xg_m2 + a2 * xs_m2;
        }
      }
      float xg = whr0_r * hn;
      if (t == 0) {
        xg += wt0_r * h0s_r;
      } else if (t == 1) {
        xg += wt1a_r * h0s_r + wt1b_r * h1;
      } else if (t == 2) {
        xg += wtg0_r * h0s_r + wtg1_r * h2 + wtg2_r * h1;
      } else {
        xg += wtg0_r * h3 + wtg1_r * h2 + wtg2_r * h1;
      }
      float xgt = rsum64(xg);
      float cu = (t == 0) ? cu0_r : (t == 1) ? cu1_r : cu2_r;
      float xsn1 = rsum64(xstw_r * Hn);
      xg_m2 = xg_m1;
      xs_m2 = xs_m1;
      xg_m1 = xgt + whb_r + cu;
      xs_m1 = xst_cur;
      xst_cur = xsn1 + xstb_r;
      h3 = h2;
      h2 = h1;
      h1 = hn;
    } else if (wid == 2) {
      float av = rsum64(wrg_r * hn);
      float bvv = rsum64(wrs_r * Hn);
      if (lane == 0) {
        float s = av + bvv;
        __hip_atomic_store(&ws[O_R + t * 66 + dd], av / s, __ATOMIC_RELAXED,
                           SC_AGENT);
        __hip_atomic_store(&ws[O_R + t * 66 + 33 + dd], bvv / s,
                           __ATOMIC_RELAXED, SC_AGENT);
      }
      asm volatile("s_waitcnt vmcnt(0)" ::: "memory");
    } else {
      out[t * DD * HH + dd * HH + lane] = Hn;
      if (t + 1 < TT && lane < HH) {
        gpre[0][lane] = ws[O_GH + (t + 1) * HH + lane];
        gpre[1][lane] = ws[O_GS + (t + 1) * HH + lane];
      }
    }
    hprev = hn;
    Hrow = Hn;
  }

  // ---- epilogue: final tags via aggregator; last 2 xpreds ----
  __syncthreads();
  if (wid == 0 && lane == 0) {
    __hip_atomic_store(&pf[(size_t)TT * 64 + dd],
                       (((unsigned long long)(unsigned)(TT + 1)) << 32),
                       __ATOMIC_RELAXED, SC_AGENT);
  }
  if (dd == 0 && wid == 0) {
    const unsigned tagv = (unsigned)(TT + 1);
    for (;;) {
      unsigned long long pk =
          (lane < NB) ? __hip_atomic_load(&pf[(size_t)TT * 64 + lane],
                                          __ATOMIC_RELAXED, SC_AGENT)
                      : (((unsigned long long)tagv) << 32);
      if (__all((int)((unsigned)(pk >> 32) == tagv))) break;
    }
    if (lane == 0)
      __hip_atomic_store(&flg[TT], tagv, __ATOMIC_RELAXED, SC_AGENT);
  }
  if (wid == 1) {
    const unsigned tagv = (unsigned)(TT + 1);
    for (;;) {
      unsigned fv = (lane == 0)
                        ? __hip_atomic_load(&flg[TT], __ATOMIC_RELAXED,
                                            SC_AGENT)
                        : 0u;
      fv = (unsigned)__shfl((int)fv, 0, 64);
      if (fv == tagv) break;
      __builtin_amdgcn_s_sleep(1);
    }
    asm volatile("" ::: "memory");
#pragma unroll 1
    for (int e = 0; e < 2; ++e) {
      const int step = TT - 2 + e;
      float r1v = -INFINITY, r2v = -INFINITY;
      if (lane < DD) {
        r1v = __hip_atomic_load(&ws[O_R + step * 66 + lane], __ATOMIC_RELAXED,
                                SC_AGENT);
        r2v = __hip_atomic_load(&ws[O_R + step * 66 + 33 + lane],
                                __ATOMIC_RELAXED, SC_AGENT);
      }
      float m1 = rmax64(r1v), m2 = rmax64(r2v);
      float e1 = (lane < DD) ? __expf(r1v - m1) : 0.f;
      float e2 = (lane < DD) ? __expf(r2v - m2) : 0.f;
      float s1 = rsum64(e1), s2 = rsum64(e2);
      float r1o = __shfl(r1v, dd, 64);
      float r2o = __shfl(r2v, dd, 64);
      if (lane == 0) {
        float a1 = __expf(r1o - m1) / s1;
        float a2 = __expf(r2o - m2) / s2;
        float xgv = (e == 0) ? xg_m2 : xg_m1;
        float xsv = (e == 0) ? xs_m2 : xs_m1;
        out[TT * DD * HH + dd * TT + step] = a1 * xgv + a2 * xsv;
      }
    }
  }
}

extern "C" void kernel_launch(void* const* d_in, const int* in_sizes, int n_in,
                              void* d_out, int out_size, void* d_ws,
                              size_t ws_size, hipStream_t stream) {
  (void)in_sizes; (void)n_in; (void)out_size; (void)ws_size;
  const float* data   = (const float*)d_in[0];
  const float* h0     = (const float*)d_in[1];
  const float* H0     = (const float*)d_in[2];
  const float* gh_w   = (const float*)d_in[3];
  const float* gh_b   = (const float*)d_in[4];
  const float* gst_w  = (const float*)d_in[5];
  const float* gst_b  = (const float*)d_in[6];
  const float* wih    = (const float*)d_in[7];
  const float* whh    = (const float*)d_in[8];
  const float* bih    = (const float*)d_in[9];
  const float* bhh    = (const float*)d_in[10];
  const float* wu0w   = (const float*)d_in[11];
  const float* wu0b   = (const float*)d_in[12];
  const float* wu1w   = (const float*)d_in[13];
  const float* wu1b   = (const float*)d_in[14];
  const float* wuw    = (const float*)d_in[15];
  const float* wub    = (const float*)d_in[16];
  const float* wh_w   = (const float*)d_in[17];
  const float* wh_b   = (const float*)d_in[18];
  const float* xst_w  = (const float*)d_in[19];
  const float* xst_b  = (const float*)d_in[20];
  const float* wrg_w  = (const float*)d_in[21];
  const float* wrs    = (const float*)d_in[22];
  const float* tWz    = (const float*)d_in[23];
  const float* tUzx   = (const float*)d_in[24];
  const float* tUzh   = (const float*)d_in[25];
  const float* tWr    = (const float*)d_in[26];
  const float* tUrx   = (const float*)d_in[27];
  const float* tUrh   = (const float*)d_in[28];
  const float* tWh    = (const float*)d_in[29];
  const float* tUhx   = (const float*)d_in[30];
  const float* tUhh   = (const float*)d_in[31];
  const float* tbz    = (const float*)d_in[32];
  const float* tbr    = (const float*)d_in[33];
  const float* tbh    = (const float*)d_in[34];

  float* ws = (float*)d_ws;
  unsigned long long* pf = (unsigned long long*)(ws + O_PF);
  unsigned* flg = (unsigned*)(ws + O_FLG);

  // zero pf ((TT+1)*64 u64) and flg ((TT+1) u32) in one contiguous memset
  hipMemsetAsync(pf, 0, (size_t)(TT + 1) * 64 * 8 + (size_t)(TT + 1) * 4,
                 stream);
  gmgru_prep<<<(PREP_N + 255) / 256, 256, 0, stream>>>(
      data, gh_w, gh_b, gst_w, gst_b, wih, whh, wu0w, wu0b, wu1w, wu1b, wuw,
      wub, wh_w, ws);
  gmgru_main<<<NB, NT, 0, stream>>>(
      data, h0, H0, bih, bhh, wh_w, wh_b, xst_w, xst_b, wrg_w, wrs, tWz, tUzx,
      tUzh, tWr, tUrx, tUrh, tWh, tUhx, tUhh, tbz, tbr, tbh, ws, pf, flg,
      (float*)d_out);
}

// Round 8
// 204.995 us; speedup vs baseline: 1.1006x; 1.1006x over previous
//
#include <hip/hip_runtime.h>
#include <math.h>

#define DD 33
#define TT 49
#define HH 64
#define NB 33
#define NT 256

// ws layout (float offsets)
#define O_WIHT  0        // 33*192 wih^T   [k*192+j]
#define O_WHHT  6336     // 64*192 whh^T   [k*192+j]
#define O_GH    18624    // 49*64  gamma_h[t][i]
#define O_GS    21760    // 49*64  gamma_st[t][i]
#define O_WT0   24896    // 33*64   wu0^T . whr1
#define O_WT1   27008    // 33*128  wu1^T . whr1
#define O_WTG   31232    // 33*192  wu^T  . whr1
#define O_CU    37568    // 33*4    whr1 . {wu0b,wu1b,wub,0}
#define O_R     37700    // 49*66   published r1(33), r2(33)
#define O_PF    40936    // 33 * PF_STRIDE u64; block-major, 1280B stride
#define PF_STRIDE 160    // u64 per block (1280 B = 5 x 256B granules)
#define PREP_N  37700

#define SC_AGENT __HIP_MEMORY_SCOPE_AGENT

__device__ __forceinline__ float sigm(float x) {
  return 1.f / (1.f + __expf(-x));
}
__device__ __forceinline__ float ftanh(float x) {
  x = fminf(fmaxf(x, -15.f), 15.f);
  float e = __expf(2.f * x);
  return (e - 1.f) / (e + 1.f);
}

__device__ __forceinline__ float rsum64(float v) {
#pragma unroll
  for (int o = 32; o > 0; o >>= 1) v += __shfl_xor(v, o, 64);
  return v;
}
__device__ __forceinline__ float rmax64(float v) {
#pragma unroll
  for (int o = 32; o > 0; o >>= 1) v = fmaxf(v, __shfl_xor(v, o, 64));
  return v;
}

extern "C" __global__ void gmgru_prep(
    const float* __restrict__ data, const float* __restrict__ gh_w,
    const float* __restrict__ gh_b, const float* __restrict__ gst_w,
    const float* __restrict__ gst_b, const float* __restrict__ wih,
    const float* __restrict__ whh, const float* __restrict__ wu0,
    const float* __restrict__ wu0b, const float* __restrict__ wu1,
    const float* __restrict__ wu1b, const float* __restrict__ wu,
    const float* __restrict__ wub, const float* __restrict__ wh_w,
    float* __restrict__ ws) {
  int idx = blockIdx.x * blockDim.x + threadIdx.x;
  if (idx < 6336) {                        // wihT[k*192+j] = wih[j*33+k]
    int k = idx / 192, j = idx % 192;
    ws[O_WIHT + idx] = wih[j * DD + k];
  } else if (idx < 18624) {                // whhT[k*192+j] = whh[j*64+k]
    int r = idx - 6336, k = r / 192, j = r % 192;
    ws[O_WHHT + r] = whh[j * HH + k];
  } else if (idx < 21760) {                // gamma_h[t][i]
    int r = idx - 18624, t = r / 64, i = r % 64;
    float s = gh_b[i];
    for (int d2 = 0; d2 < DD; ++d2)
      s += data[2 * DD * TT + d2 * TT + t] * gh_w[i * DD + d2];
    ws[O_GH + r] = expf(-fmaxf(s, 0.f));
  } else if (idx < 24896) {                // gamma_st[t][i]
    int r = idx - 21760, t = r / 64, i = r % 64;
    float s = gst_b[i];
    for (int d2 = 0; d2 < DD; ++d2)
      s += data[2 * DD * TT + d2 * TT + t] * gst_w[i * DD + d2];
    ws[O_GS + r] = expf(-fmaxf(s, 0.f));
  } else if (idx < 27008) {                // wt0[dd][k] = sum_q wu0[q][k]*whr1[q]
    int r = idx - 24896, dd = r / 64, k = r % 64;
    float s = 0.f;
    for (int q = 0; q < 64; ++q) s += wu0[q * 64 + k] * wh_w[dd * 128 + 64 + q];
    ws[O_WT0 + r] = s;
  } else if (idx < 31232) {                // wt1[dd][k]
    int r = idx - 27008, dd = r / 128, k = r % 128;
    float s = 0.f;
    for (int q = 0; q < 64; ++q) s += wu1[q * 128 + k] * wh_w[dd * 128 + 64 + q];
    ws[O_WT1 + r] = s;
  } else if (idx < 37568) {                // wtg[dd][k]
    int r = idx - 31232, dd = r / 192, k = r % 192;
    float s = 0.f;
    for (int q = 0; q < 64; ++q) s += wu[q * 192 + k] * wh_w[dd * 128 + 64 + q];
    ws[O_WTG + r] = s;
  } else if (idx < PREP_N) {               // cu[dd][v] = whr1 . bias_v
    int r = idx - 37568, dd = r / 4, v = r % 4;
    float s = 0.f;
    if (v < 3) {
      const float* bp = (v == 0) ? wu0b : (v == 1) ? wu1b : wub;
      for (int q = 0; q < 64; ++q) s += bp[q] * wh_w[dd * 128 + 64 + q];
    }
    ws[O_CU + r] = s;
  }
}

extern "C" __global__ void __launch_bounds__(NT, 1)
gmgru_main(const float* __restrict__ data, const float* __restrict__ h0,
           const float* __restrict__ H0, const float* __restrict__ bih,
           const float* __restrict__ bhh, const float* __restrict__ wh_w,
           const float* __restrict__ wh_b, const float* __restrict__ xst_w,
           const float* __restrict__ xst_b, const float* __restrict__ wrg_w,
           const float* __restrict__ wrs, const float* __restrict__ tWz,
           const float* __restrict__ tUzx, const float* __restrict__ tUzh,
           const float* __restrict__ tWr, const float* __restrict__ tUrx,
           const float* __restrict__ tUrh, const float* __restrict__ tWh,
           const float* __restrict__ tUhx, const float* __restrict__ tUhh,
           const float* __restrict__ tbz, const float* __restrict__ tbr,
           const float* __restrict__ tbh, float* __restrict__ ws,
           unsigned long long* __restrict__ pf, float* __restrict__ out) {
  __shared__ __attribute__((aligned(16))) float ubuf[3][4096];  // 48 KB
  __shared__ float whhT_l[12288];                               // 48 KB
  __shared__ float wihT_l[6336];                                // 25 KB
  __shared__ float partW[3][4][HH], partU[3][4][HH];            // 6 KB
  __shared__ float hpreL[HH], hnewL[HH], ghLDS[3 * HH];
  __shared__ float gpre[2][HH];
  __shared__ float xrow[TT], mrow[TT];
  __shared__ float xcddL;

  const int tid = threadIdx.x;
  const int dd = blockIdx.x;
  const int wid = tid >> 6;
  const int lane = tid & 63;

  // ---- one-time staging ----
  {
    const float* usrc[3] = {tUzh, tUrh, tUhh};
#pragma unroll 1
    for (int m = 0; m < 3; ++m) {
      const float* s = usrc[m] + dd * 4096;
#pragma unroll
      for (int c = 0; c < 4; ++c) {
        int f = tid * 16 + c * 4;  // source flat idx (i*64+k)
        float4 v = *reinterpret_cast<const float4*>(s + f);
        int i = f >> 6, k = f & 63;
        *reinterpret_cast<float4*>(&ubuf[m][(k >> 2) * 256 + i * 4]) = v;
      }
    }
  }
  for (int i = tid; i < 12288; i += NT) whhT_l[i] = ws[O_WHHT + i];
  for (int i = tid; i < 6336; i += NT) wihT_l[i] = ws[O_WIHT + i];
  if (tid < HH) {
    gpre[0][tid] = ws[O_GH + tid];
    gpre[1][tid] = ws[O_GS + tid];
  }
  if (tid < TT) {
    xrow[tid] = data[dd * TT + tid];
    mrow[tid] = data[DD * TT + dd * TT + tid];
  }
  // per-lane registers
  const float bih_r = bih[lane];
  const float bih_z = bih[64 + lane];
  const float bih_n = bih[128 + lane];
  const float bhh_r = (tid < 192) ? bhh[tid] : 0.f;
  const float ux0 = tUzx[dd * HH + lane];
  const float ux1 = tUrx[dd * HH + lane];
  const float ux2 = tUhx[dd * HH + lane];
  const float tb0 = tbz[lane];
  const float tb1 = tbr[lane];
  const float tb2 = tbh[lane];
  const float xstw_r = xst_w[lane];
  const float wrg_r = wrg_w[dd * HH + lane];
  const float wrs_r = wrs[lane];
  const float whr0_r = wh_w[dd * 128 + lane];
  const float wtg0_r = ws[O_WTG + dd * 192 + lane];
  const float wtg1_r = ws[O_WTG + dd * 192 + 64 + lane];
  const float wtg2_r = ws[O_WTG + dd * 192 + 128 + lane];
  const float wt0_r = ws[O_WT0 + dd * 64 + lane];
  const float wt1a_r = ws[O_WT1 + dd * 128 + lane];
  const float wt1b_r = ws[O_WT1 + dd * 128 + 64 + lane];
  const float cu0_r = ws[O_CU + dd * 4 + 0];
  const float cu1_r = ws[O_CU + dd * 4 + 1];
  const float cu2_r = ws[O_CU + dd * 4 + 2];
  const float whb_r = wh_b[dd];
  const float xstb_r = xst_b[0];
  const float h0s_r = h0[lane];
  float hprev = h0s_r;
  float Hrow = H0[dd * HH + lane];
  __syncthreads();

  // ---- prologue: x_st(0); publish slot[dd][0] = {tag 1, xc(0)} ----
  float xst_cur = rsum64(Hrow * xstw_r) + xstb_r;
  if (wid == 0 && lane == 0) {
    float xc0 = mrow[0] * xrow[0] + (1.f - mrow[0]) * xst_cur;
    unsigned long long pk0 =
        (1ULL << 32) | (unsigned long long)__float_as_uint(xc0);
    __hip_atomic_store(&pf[(size_t)dd * PF_STRIDE], pk0, __ATOMIC_RELAXED,
                       SC_AGENT);
  }
  // wave1 rings (registers)
  float xg_m1 = 0.f, xg_m2 = 0.f, xs_m1 = 0.f, xs_m2 = 0.f;
  float h1 = 0.f, h2 = 0.f, h3 = 0.f;

  for (int t = 0; t < TT; ++t) {
    __syncthreads();  // S0: prev wave3 gpre write -> this-step reads
    float hpre_r = gpre[0][lane] * hprev;
    float Hdec_r = gpre[1][lane] * Hrow;
    if (wid == 0) hpreL[lane] = hpre_r;
    __syncthreads();  // S1

    // ---- pre-phase (off critical path): W-half from global + gh_ GEMV ----
    {
      float pw0 = 0.f, pw1 = 0.f, pw2 = 0.f;
      const int base = dd * 4096 + lane * 64 + wid * 16;
#pragma unroll
      for (int g = 0; g < 4; ++g) {
        float4 a = *reinterpret_cast<const float4*>(tWz + base + g * 4);
        float4 bb = *reinterpret_cast<const float4*>(tWr + base + g * 4);
        float4 c = *reinterpret_cast<const float4*>(tWh + base + g * 4);
        float v0 = __shfl(Hdec_r, wid * 16 + g * 4 + 0, 64);
        float v1 = __shfl(Hdec_r, wid * 16 + g * 4 + 1, 64);
        float v2 = __shfl(Hdec_r, wid * 16 + g * 4 + 2, 64);
        float v3 = __shfl(Hdec_r, wid * 16 + g * 4 + 3, 64);
        pw0 += a.x * v0 + a.y * v1 + a.z * v2 + a.w * v3;
        pw1 += bb.x * v0 + bb.y * v1 + bb.z * v2 + bb.w * v3;
        pw2 += c.x * v0 + c.y * v1 + c.z * v2 + c.w * v3;
      }
      partW[0][wid][lane] = pw0;
      partW[1][wid][lane] = pw1;
      partW[2][wid][lane] = pw2;
    }
    if (tid < 3 * HH) {
      float a0 = 0.f, a1 = 0.f, a2 = 0.f, a3 = 0.f;
#pragma unroll
      for (int k = 0; k < HH; k += 4) {
        a0 += whhT_l[(k + 0) * 192 + tid] * hpreL[k + 0];
        a1 += whhT_l[(k + 1) * 192 + tid] * hpreL[k + 1];
        a2 += whhT_l[(k + 2) * 192 + tid] * hpreL[k + 2];
        a3 += whhT_l[(k + 3) * 192 + tid] * hpreL[k + 3];
      }
      ghLDS[tid] = bhh_r + ((a0 + a1) + (a2 + a3));
    }
    __syncthreads();  // S_b: ghLDS/partW ready before wave0's post-spin reads

    // ---- wave0: spin on channel-spread slots; exit delivers xc ----
    float hn = 0.f;
    if (wid == 0) {
      const unsigned tagv = (unsigned)(t + 1);
      unsigned long long pk;
      for (;;) {
        pk = (lane < NB)
                 ? __hip_atomic_load(&pf[(size_t)lane * PF_STRIDE + t],
                                     __ATOMIC_RELAXED, SC_AGENT)
                 : (((unsigned long long)tagv) << 32);
        if (__all((int)((unsigned)(pk >> 32) == tagv))) break;
        __builtin_amdgcn_s_sleep(1);
      }
      float xcv = __uint_as_float((unsigned)(pk & 0xFFFFFFFFull));
      asm volatile("" ::: "memory");
      float gr = bih_r, gz = bih_z, gn = bih_n;
#pragma unroll
      for (int k = 0; k < DD; ++k) {
        float xk = __shfl(xcv, k, 64);
        gr += wihT_l[k * 192 + lane] * xk;
        gz += wihT_l[k * 192 + 64 + lane] * xk;
        gn += wihT_l[k * 192 + 128 + lane] * xk;
      }
      float rg = sigm(gr + ghLDS[lane]);
      float zg = sigm(gz + ghLDS[64 + lane]);
      float ng = ftanh(gn + rg * ghLDS[128 + lane]);
      hn = (1.f - zg) * ng + zg * hpre_r;
      hnewL[lane] = hn;
      float xcd = __shfl(xcv, dd, 64);
      if (lane == 0) xcddL = xcd;
    }
    __syncthreads();  // S3

    // ---- U-half partials from LDS (all waves) ----
    {
      float hv[16];
#pragma unroll
      for (int j = 0; j < 16; ++j) hv[j] = hnewL[wid * 16 + j];
      float pu0 = 0.f, pu1 = 0.f, pu2 = 0.f;
#pragma unroll
      for (int g = 0; g < 4; ++g) {
        const int kg = (wid * 4 + g) * 256 + lane * 4;
        float4 a = *reinterpret_cast<const float4*>(&ubuf[0][kg]);
        float4 bb = *reinterpret_cast<const float4*>(&ubuf[1][kg]);
        float4 c = *reinterpret_cast<const float4*>(&ubuf[2][kg]);
        const float v0 = hv[g * 4 + 0], v1 = hv[g * 4 + 1];
        const float v2 = hv[g * 4 + 2], v3 = hv[g * 4 + 3];
        pu0 += a.x * v0 + a.y * v1 + a.z * v2 + a.w * v3;
        pu1 += bb.x * v0 + bb.y * v1 + bb.z * v2 + bb.w * v3;
        pu2 += c.x * v0 + c.y * v1 + c.z * v2 + c.w * v3;
      }
      partU[0][wid][lane] = pu0;
      partU[1][wid][lane] = pu1;
      partU[2][wid][lane] = pu2;
    }
    __syncthreads();  // S4

    // wave1: issue r(t-2) gather early (hides under combine)
    float r1v = -INFINITY, r2v = -INFINITY;
    if (wid == 1 && t >= 2 && lane < DD) {
      r1v = __hip_atomic_load(&ws[O_R + (t - 2) * 66 + lane], __ATOMIC_RELAXED,
                              SC_AGENT);
      r2v = __hip_atomic_load(&ws[O_R + (t - 2) * 66 + 33 + lane],
                              __ATOMIC_RELAXED, SC_AGENT);
    }

    // ---- combine (redundant per wave) -> H_t ----
    float sz = partW[0][0][lane] + partW[0][1][lane] + partW[0][2][lane] +
               partW[0][3][lane] + partU[0][0][lane] + partU[0][1][lane] +
               partU[0][2][lane] + partU[0][3][lane];
    float sr = partW[1][0][lane] + partW[1][1][lane] + partW[1][2][lane] +
               partW[1][3][lane] + partU[1][0][lane] + partU[1][1][lane] +
               partU[1][2][lane] + partU[1][3][lane];
    float swh = partW[2][0][lane] + partW[2][1][lane] + partW[2][2][lane] +
                partW[2][3][lane];
    float suh = partU[2][0][lane] + partU[2][1][lane] + partU[2][2][lane] +
                partU[2][3][lane];
    float xc = xcddL;
    float z2 = sigm(sz + ux0 * xc + tb0);
    float r2g = sigm(sr + ux1 * xc + tb1);
    float hh = ftanh(r2g * swh + ux2 * xc + suh + tb2);
    float Hn = z2 * Hdec_r + (1.f - z2) * hh;
    if (wid != 0) hn = hnewL[lane];

    // ---- role split ----
    if (wid == 0) {
      float xsn = rsum64(xstw_r * Hn);
      if (lane == 0 && t < TT - 1) {
        float xstv = xsn + xstb_r;
        float xcn = mrow[t + 1] * xrow[t + 1] + (1.f - mrow[t + 1]) * xstv;
        unsigned long long pkn =
            (((unsigned long long)(unsigned)(t + 2)) << 32) |
            (unsigned long long)__float_as_uint(xcn);
        __hip_atomic_store(&pf[(size_t)dd * PF_STRIDE + (t + 1)], pkn,
                           __ATOMIC_RELAXED, SC_AGENT);
      }
    } else if (wid == 1) {
      if (t >= 2) {
        float m1 = rmax64(r1v), m2 = rmax64(r2v);
        float e1 = (lane < DD) ? __expf(r1v - m1) : 0.f;
        float e2 = (lane < DD) ? __expf(r2v - m2) : 0.f;
        float s1 = rsum64(e1), s2 = rsum64(e2);
        float r1o = __shfl(r1v, dd, 64);
        float r2o = __shfl(r2v, dd, 64);
        if (lane == 0) {
          float a1 = __expf(r1o - m1) / s1;
          float a2 = __expf(r2o - m2) / s2;
          out[TT * DD * HH + dd * TT + (t - 2)] = a1 * xg_m2 + a2 * xs_m2;
        }
      }
      float xg = whr0_r * hn;
      if (t == 0) {
        xg += wt0_r * h0s_r;
      } else if (t == 1) {
        xg += wt1a_r * h0s_r + wt1b_r * h1;
      } else if (t == 2) {
        xg += wtg0_r * h0s_r + wtg1_r * h2 + wtg2_r * h1;
      } else {
        xg += wtg0_r * h3 + wtg1_r * h2 + wtg2_r * h1;
      }
      float xgt = rsum64(xg);
      float cu = (t == 0) ? cu0_r : (t == 1) ? cu1_r : cu2_r;
      float xsn1 = rsum64(xstw_r * Hn);
      xg_m2 = xg_m1;
      xs_m2 = xs_m1;
      xg_m1 = xgt + whb_r + cu;
      xs_m1 = xst_cur;
      xst_cur = xsn1 + xstb_r;
      h3 = h2;
      h2 = h1;
      h1 = hn;
    } else if (wid == 2) {
      float av = rsum64(wrg_r * hn);
      float bvv = rsum64(wrs_r * Hn);
      if (lane == 0) {
        float s = av + bvv;
        __hip_atomic_store(&ws[O_R + t * 66 + dd], av / s, __ATOMIC_RELAXED,
                           SC_AGENT);
        __hip_atomic_store(&ws[O_R + t * 66 + 33 + dd], bvv / s,
                           __ATOMIC_RELAXED, SC_AGENT);
      }
      asm volatile("s_waitcnt vmcnt(0)" ::: "memory");
    } else {
      out[t * DD * HH + dd * HH + lane] = Hn;
      if (t + 1 < TT && lane < HH) {
        gpre[0][lane] = ws[O_GH + (t + 1) * HH + lane];
        gpre[1][lane] = ws[O_GS + (t + 1) * HH + lane];
      }
    }
    hprev = hn;
    Hrow = Hn;
  }

  // ---- epilogue: final tag (covers r(TT-2), r(TT-1)); last 2 xpreds ----
  __syncthreads();
  if (wid == 0 && lane == 0) {
    __hip_atomic_store(&pf[(size_t)dd * PF_STRIDE + TT],
                       (((unsigned long long)(unsigned)(TT + 1)) << 32),
                       __ATOMIC_RELAXED, SC_AGENT);
  }
  if (wid == 1) {
    const unsigned tagv = (unsigned)(TT + 1);
    for (;;) {
      unsigned long long pk =
          (lane < NB) ? __hip_atomic_load(&pf[(size_t)lane * PF_STRIDE + TT],
                                          __ATOMIC_RELAXED, SC_AGENT)
                      : (((unsigned long long)tagv) << 32);
      if (__all((int)((unsigned)(pk >> 32) == tagv))) break;
      __builtin_amdgcn_s_sleep(1);
    }
    asm volatile("" ::: "memory");
#pragma unroll 1
    for (int e = 0; e < 2; ++e) {
      const int step = TT - 2 + e;
      float r1v = -INFINITY, r2v = -INFINITY;
      if (lane < DD) {
        r1v = __hip_atomic_load(&ws[O_R + step * 66 + lane], __ATOMIC_RELAXED,
                                SC_AGENT);
        r2v = __hip_atomic_load(&ws[O_R + step * 66 + 33 + lane],
                                __ATOMIC_RELAXED, SC_AGENT);
      }
      float m1 = rmax64(r1v), m2 = rmax64(r2v);
      float e1 = (lane < DD) ? __expf(r1v - m1) : 0.f;
      float e2 = (lane < DD) ? __expf(r2v - m2) : 0.f;
      float s1 = rsum64(e1), s2 = rsum64(e2);
      float r1o = __shfl(r1v, dd, 64);
      float r2o = __shfl(r2v, dd, 64);
      if (lane == 0) {
        float a1 = __expf(r1o - m1) / s1;
        float a2 = __expf(r2o - m2) / s2;
        float xgv = (e == 0) ? xg_m2 : xg_m1;
        float xsv = (e == 0) ? xs_m2 : xs_m1;
        out[TT * DD * HH + dd * TT + step] = a1 * xgv + a2 * xsv;
      }
    }
  }
}

extern "C" void kernel_launch(void* const* d_in, const int* in_sizes, int n_in,
                              void* d_out, int out_size, void* d_ws,
                              size_t ws_size, hipStream_t stream) {
  (void)in_sizes; (void)n_in; (void)out_size; (void)ws_size;
  const float* data   = (const float*)d_in[0];
  const float* h0     = (const float*)d_in[1];
  const float* H0     = (const float*)d_in[2];
  const float* gh_w   = (const float*)d_in[3];
  const float* gh_b   = (const float*)d_in[4];
  const float* gst_w  = (const float*)d_in[5];
  const float* gst_b  = (const float*)d_in[6];
  const float* wih    = (const float*)d_in[7];
  const float* whh    = (const float*)d_in[8];
  const float* bih    = (const float*)d_in[9];
  const float* bhh    = (const float*)d_in[10];
  const float* wu0w   = (const float*)d_in[11];
  const float* wu0b   = (const float*)d_in[12];
  const float* wu1w   = (const float*)d_in[13];
  const float* wu1b   = (const float*)d_in[14];
  const float* wuw    = (const float*)d_in[15];
  const float* wub    = (const float*)d_in[16];
  const float* wh_w   = (const float*)d_in[17];
  const float* wh_b   = (const float*)d_in[18];
  const float* xst_w  = (const float*)d_in[19];
  const float* xst_b  = (const float*)d_in[20];
  const float* wrg_w  = (const float*)d_in[21];
  const float* wrs    = (const float*)d_in[22];
  const float* tWz    = (const float*)d_in[23];
  const float* tUzx   = (const float*)d_in[24];
  const float* tUzh   = (const float*)d_in[25];
  const float* tWr    = (const float*)d_in[26];
  const float* tUrx   = (const float*)d_in[27];
  const float* tUrh   = (const float*)d_in[28];
  const float* tWh    = (const float*)d_in[29];
  const float* tUhx   = (const float*)d_in[30];
  const float* tUhh   = (const float*)d_in[31];
  const float* tbz    = (const float*)d_in[32];
  const float* tbr    = (const float*)d_in[33];
  const float* tbh    = (const float*)d_in[34];

  float* ws = (float*)d_ws;
  unsigned long long* pf = (unsigned long long*)(ws + O_PF);

  hipMemsetAsync(pf, 0, (size_t)NB * PF_STRIDE * 8, stream);
  gmgru_prep<<<(PREP_N + 255) / 256, 256, 0, stream>>>(
      data, gh_w, gh_b, gst_w, gst_b, wih, whh, wu0w, wu0b, wu1w, wu1b, wuw,
      wub, wh_w, ws);
  gmgru_main<<<NB, NT, 0, stream>>>(
      data, h0, H0, bih, bhh, wh_w, wh_b, xst_w, xst_b, wrg_w, wrs, tWz, tUzx,
      tUzh, tWr, tUrx, tUrh, tWh, tUhx, tUhh, tbz, tbr, tbh, ws, pf,
      (float*)d_out);
}

// Round 9
// 196.270 us; speedup vs baseline: 1.1496x; 1.0445x over previous
//
#include <hip/hip_runtime.h>
#include <math.h>

#define DD 33
#define TT 49
#define HH 64
#define NB 33
#define NT 256

// ws layout (float offsets) — identical to round 8
#define O_WIHT  0        // 33*192 wih^T   [k*192+j]
#define O_WHHT  6336     // 64*192 whh^T   [k*192+j]
#define O_GH    18624    // 49*64  gamma_h[t][i]
#define O_GS    21760    // 49*64  gamma_st[t][i]
#define O_WT0   24896    // 33*64   wu0^T . whr1
#define O_WT1   27008    // 33*128  wu1^T . whr1
#define O_WTG   31232    // 33*192  wu^T  . whr1
#define O_CU    37568    // 33*4    whr1 . {wu0b,wu1b,wub,0}
#define O_R     37700    // 49*66   published r1(33), r2(33)
#define O_PF    40936    // 33 * PF_STRIDE u64; block-major, 1280B stride
#define PF_STRIDE 160    // u64 per block (1280 B = 5 x 256B granules)
#define PREP_N  37700

#define SC_AGENT __HIP_MEMORY_SCOPE_AGENT

__device__ __forceinline__ float sigm(float x) {
  return 1.f / (1.f + __expf(-x));
}
__device__ __forceinline__ float ftanh(float x) {
  x = fminf(fmaxf(x, -15.f), 15.f);
  float e = __expf(2.f * x);
  return (e - 1.f) / (e + 1.f);
}

__device__ __forceinline__ float rsum64(float v) {
#pragma unroll
  for (int o = 32; o > 0; o >>= 1) v += __shfl_xor(v, o, 64);
  return v;
}
__device__ __forceinline__ float rmax64(float v) {
#pragma unroll
  for (int o = 32; o > 0; o >>= 1) v = fmaxf(v, __shfl_xor(v, o, 64));
  return v;
}

extern "C" __global__ void gmgru_prep(
    const float* __restrict__ data, const float* __restrict__ gh_w,
    const float* __restrict__ gh_b, const float* __restrict__ gst_w,
    const float* __restrict__ gst_b, const float* __restrict__ wih,
    const float* __restrict__ whh, const float* __restrict__ wu0,
    const float* __restrict__ wu0b, const float* __restrict__ wu1,
    const float* __restrict__ wu1b, const float* __restrict__ wu,
    const float* __restrict__ wub, const float* __restrict__ wh_w,
    float* __restrict__ ws) {
  int idx = blockIdx.x * blockDim.x + threadIdx.x;
  if (idx < 6336) {                        // wihT[k*192+j] = wih[j*33+k]
    int k = idx / 192, j = idx % 192;
    ws[O_WIHT + idx] = wih[j * DD + k];
  } else if (idx < 18624) {                // whhT[k*192+j] = whh[j*64+k]
    int r = idx - 6336, k = r / 192, j = r % 192;
    ws[O_WHHT + r] = whh[j * HH + k];
  } else if (idx < 21760) {                // gamma_h[t][i]
    int r = idx - 18624, t = r / 64, i = r % 64;
    float s = gh_b[i];
    for (int d2 = 0; d2 < DD; ++d2)
      s += data[2 * DD * TT + d2 * TT + t] * gh_w[i * DD + d2];
    ws[O_GH + r] = expf(-fmaxf(s, 0.f));
  } else if (idx < 24896) {                // gamma_st[t][i]
    int r = idx - 21760, t = r / 64, i = r % 64;
    float s = gst_b[i];
    for (int d2 = 0; d2 < DD; ++d2)
      s += data[2 * DD * TT + d2 * TT + t] * gst_w[i * DD + d2];
    ws[O_GS + r] = expf(-fmaxf(s, 0.f));
  } else if (idx < 27008) {                // wt0[dd][k] = sum_q wu0[q][k]*whr1[q]
    int r = idx - 24896, dd = r / 64, k = r % 64;
    float s = 0.f;
    for (int q = 0; q < 64; ++q) s += wu0[q * 64 + k] * wh_w[dd * 128 + 64 + q];
    ws[O_WT0 + r] = s;
  } else if (idx < 31232) {                // wt1[dd][k]
    int r = idx - 27008, dd = r / 128, k = r % 128;
    float s = 0.f;
    for (int q = 0; q < 64; ++q) s += wu1[q * 128 + k] * wh_w[dd * 128 + 64 + q];
    ws[O_WT1 + r] = s;
  } else if (idx < 37568) {                // wtg[dd][k]
    int r = idx - 31232, dd = r / 192, k = r % 192;
    float s = 0.f;
    for (int q = 0; q < 64; ++q) s += wu[q * 192 + k] * wh_w[dd * 128 + 64 + q];
    ws[O_WTG + r] = s;
  } else if (idx < PREP_N) {               // cu[dd][v] = whr1 . bias_v
    int r = idx - 37568, dd = r / 4, v = r % 4;
    float s = 0.f;
    if (v < 3) {
      const float* bp = (v == 0) ? wu0b : (v == 1) ? wu1b : wub;
      for (int q = 0; q < 64; ++q) s += bp[q] * wh_w[dd * 128 + 64 + q];
    }
    ws[O_CU + r] = s;
  }
}

extern "C" __global__ void __launch_bounds__(NT, 1)
gmgru_main(const float* __restrict__ data, const float* __restrict__ h0,
           const float* __restrict__ H0, const float* __restrict__ bih,
           const float* __restrict__ bhh, const float* __restrict__ wh_w,
           const float* __restrict__ wh_b, const float* __restrict__ xst_w,
           const float* __restrict__ xst_b, const float* __restrict__ wrg_w,
           const float* __restrict__ wrs, const float* __restrict__ tWz,
           const float* __restrict__ tUzx, const float* __restrict__ tUzh,
           const float* __restrict__ tWr, const float* __restrict__ tUrx,
           const float* __restrict__ tUrh, const float* __restrict__ tWh,
           const float* __restrict__ tUhx, const float* __restrict__ tUhh,
           const float* __restrict__ tbz, const float* __restrict__ tbr,
           const float* __restrict__ tbh, float* __restrict__ ws,
           unsigned long long* __restrict__ pf, float* __restrict__ out) {
  __shared__ float whhT_l[12288];                 // 48 KB
  __shared__ float wihT_l[6336];                  // 25 KB
  __shared__ float part[2][6][4][HH];             // 12 KB dbuf
  __shared__ float ghL[3 * HH], giL[3 * HH];
  __shared__ float xrow[TT], mrow[TT];

  const int tid = threadIdx.x;
  const int dd = blockIdx.x;
  const int wid = tid >> 6;
  const int lane = tid & 63;

  // ---- one-time staging ----
  for (int i = tid; i < 12288; i += NT) whhT_l[i] = ws[O_WHHT + i];
  for (int i = tid; i < 6336; i += NT) wihT_l[i] = ws[O_WIHT + i];
  if (tid < TT) {
    xrow[tid] = data[dd * TT + tid];
    mrow[tid] = data[DD * TT + dd * TT + tid];
  }
  // U-half tensor weights -> registers (thread covers k = wid*16..wid*16+15)
  float4 u0[4], u1[4], u2[4];
  {
    const int base = dd * 4096 + lane * 64 + wid * 16;
#pragma unroll
    for (int g = 0; g < 4; ++g) {
      u0[g] = *reinterpret_cast<const float4*>(tUzh + base + g * 4);
      u1[g] = *reinterpret_cast<const float4*>(tUrh + base + g * 4);
      u2[g] = *reinterpret_cast<const float4*>(tUhh + base + g * 4);
    }
  }
  // per-lane registers
  const float bih_r = (tid < 192) ? bih[tid] : 0.f;
  const float bhh_r = (tid < 192) ? bhh[tid] : 0.f;
  const float ux0 = tUzx[dd * HH + lane];
  const float ux1 = tUrx[dd * HH + lane];
  const float ux2 = tUhx[dd * HH + lane];
  const float tb0 = tbz[lane];
  const float tb1 = tbr[lane];
  const float tb2 = tbh[lane];
  const float xstw_r = xst_w[lane];
  const float wrg_r = wrg_w[dd * HH + lane];
  const float wrs_r = wrs[lane];
  const float whr0_r = wh_w[dd * 128 + lane];
  const float wtg0_r = ws[O_WTG + dd * 192 + lane];
  const float wtg1_r = ws[O_WTG + dd * 192 + 64 + lane];
  const float wtg2_r = ws[O_WTG + dd * 192 + 128 + lane];
  const float wt0_r = ws[O_WT0 + dd * 64 + lane];
  const float wt1a_r = ws[O_WT1 + dd * 128 + lane];
  const float wt1b_r = ws[O_WT1 + dd * 128 + 64 + lane];
  const float cu0_r = ws[O_CU + dd * 4 + 0];
  const float cu1_r = ws[O_CU + dd * 4 + 1];
  const float cu2_r = ws[O_CU + dd * 4 + 2];
  const float whb_r = wh_b[dd];
  const float xstb_r = xst_b[0];
  const float h0s_r = h0[lane];
  float hprev = h0s_r;
  float Hrow = H0[dd * HH + lane];
  float gH_cur = ws[O_GH + lane];
  float gS_cur = ws[O_GS + lane];
  __syncthreads();

  // ---- prologue: x_st(0); publish slot[dd][0] = {tag 1, xc(0)} ----
  float xst_cur = rsum64(Hrow * xstw_r) + xstb_r;
  if (wid == 0 && lane == 0) {
    float xc0 = mrow[0] * xrow[0] + (1.f - mrow[0]) * xst_cur;
    unsigned long long pk0 =
        (1ULL << 32) | (unsigned long long)__float_as_uint(xc0);
    __hip_atomic_store(&pf[(size_t)dd * PF_STRIDE], pk0, __ATOMIC_RELAXED,
                       SC_AGENT);
  }
  // wave1 rings (registers)
  float xg_m1 = 0.f, xg_m2 = 0.f, xs_m1 = 0.f, xs_m2 = 0.f;
  float h1 = 0.f, h2 = 0.f, h3 = 0.f;

  for (int t = 0; t < TT; ++t) {
    const int b = t & 1;
    float hpre_r = gH_cur * hprev;
    float Hdec_r = gS_cur * Hrow;
    // prefetch next gammas (consumed next iteration -> latency hidden)
    float gH_nxt = 0.f, gS_nxt = 0.f;
    if (t + 1 < TT) {
      gH_nxt = ws[O_GH + (t + 1) * HH + lane];
      gS_nxt = ws[O_GS + (t + 1) * HH + lane];
    }

    // ---- pre-phase: W-half partials from global; gh_ GEMV via shfl ----
    {
      float pw0 = 0.f, pw1 = 0.f, pw2 = 0.f;
      const int base = dd * 4096 + lane * 64 + wid * 16;
#pragma unroll
      for (int g = 0; g < 4; ++g) {
        float4 a = *reinterpret_cast<const float4*>(tWz + base + g * 4);
        float4 bb = *reinterpret_cast<const float4*>(tWr + base + g * 4);
        float4 c = *reinterpret_cast<const float4*>(tWh + base + g * 4);
        float v0 = __shfl(Hdec_r, wid * 16 + g * 4 + 0, 64);
        float v1 = __shfl(Hdec_r, wid * 16 + g * 4 + 1, 64);
        float v2 = __shfl(Hdec_r, wid * 16 + g * 4 + 2, 64);
        float v3 = __shfl(Hdec_r, wid * 16 + g * 4 + 3, 64);
        pw0 += a.x * v0 + a.y * v1 + a.z * v2 + a.w * v3;
        pw1 += bb.x * v0 + bb.y * v1 + bb.z * v2 + bb.w * v3;
        pw2 += c.x * v0 + c.y * v1 + c.z * v2 + c.w * v3;
      }
      part[b][0][wid][lane] = pw0;
      part[b][1][wid][lane] = pw1;
      part[b][2][wid][lane] = pw2;
    }
    if (tid < 3 * HH) {
      float a0 = 0.f, a1 = 0.f, a2 = 0.f, a3 = 0.f;
#pragma unroll
      for (int k = 0; k < HH; k += 4) {
        a0 += whhT_l[(k + 0) * 192 + tid] * __shfl(hpre_r, k + 0, 64);
        a1 += whhT_l[(k + 1) * 192 + tid] * __shfl(hpre_r, k + 1, 64);
        a2 += whhT_l[(k + 2) * 192 + tid] * __shfl(hpre_r, k + 2, 64);
        a3 += whhT_l[(k + 3) * 192 + tid] * __shfl(hpre_r, k + 3, 64);
      }
      ghL[tid] = bhh_r + ((a0 + a1) + (a2 + a3));
    }
    __syncthreads();  // S_b: ghL + part-W ready

    // ---- spin: all waves (delivers xcv per wave) ----
    const unsigned tagv = (unsigned)(t + 1);
    unsigned long long pk;
    for (;;) {
      pk = (lane < NB)
               ? __hip_atomic_load(&pf[(size_t)lane * PF_STRIDE + t],
                                   __ATOMIC_RELAXED, SC_AGENT)
               : (((unsigned long long)tagv) << 32);
      if (__all((int)((unsigned)(pk >> 32) == tagv))) break;
      __builtin_amdgcn_s_sleep(1);
    }
    float xcv = __uint_as_float((unsigned)(pk & 0xFFFFFFFFull));
    asm volatile("" ::: "memory");

    // ---- gi partials: split across waves 0..2 (33 LDS reads each) ----
    if (tid < 3 * HH) {
      float gi = bih_r;
#pragma unroll
      for (int k = 0; k < DD; ++k)
        gi += wihT_l[k * 192 + tid] * __shfl(xcv, k, 64);
      giL[tid] = gi;
    }
    __syncthreads();  // S3

    // ---- h_t (redundant, all waves) ----
    float rg = sigm(giL[lane] + ghL[lane]);
    float zg = sigm(giL[64 + lane] + ghL[64 + lane]);
    float ng = ftanh(giL[128 + lane] + rg * ghL[128 + lane]);
    float hn = (1.f - zg) * ng + zg * hpre_r;

    // ---- U-half partials from registers ----
    {
      float pu0 = 0.f, pu1 = 0.f, pu2 = 0.f;
#pragma unroll
      for (int g = 0; g < 4; ++g) {
        float v0 = __shfl(hn, wid * 16 + g * 4 + 0, 64);
        float v1 = __shfl(hn, wid * 16 + g * 4 + 1, 64);
        float v2 = __shfl(hn, wid * 16 + g * 4 + 2, 64);
        float v3 = __shfl(hn, wid * 16 + g * 4 + 3, 64);
        pu0 += u0[g].x * v0 + u0[g].y * v1 + u0[g].z * v2 + u0[g].w * v3;
        pu1 += u1[g].x * v0 + u1[g].y * v1 + u1[g].z * v2 + u1[g].w * v3;
        pu2 += u2[g].x * v0 + u2[g].y * v1 + u2[g].z * v2 + u2[g].w * v3;
      }
      part[b][3][wid][lane] = pu0;
      part[b][4][wid][lane] = pu1;
      part[b][5][wid][lane] = pu2;
    }
    __syncthreads();  // S4

    // wave1: issue r(t-2) gather early (hides under combine)
    float r1v = -INFINITY, r2v = -INFINITY;
    if (wid == 1 && t >= 2 && lane < DD) {
      r1v = __hip_atomic_load(&ws[O_R + (t - 2) * 66 + lane], __ATOMIC_RELAXED,
                              SC_AGENT);
      r2v = __hip_atomic_load(&ws[O_R + (t - 2) * 66 + 33 + lane],
                              __ATOMIC_RELAXED, SC_AGENT);
    }

    // ---- combine (redundant per wave) -> H_t ----
    float sz = part[b][0][0][lane] + part[b][0][1][lane] + part[b][0][2][lane] +
               part[b][0][3][lane] + part[b][3][0][lane] + part[b][3][1][lane] +
               part[b][3][2][lane] + part[b][3][3][lane];
    float sr = part[b][1][0][lane] + part[b][1][1][lane] + part[b][1][2][lane] +
               part[b][1][3][lane] + part[b][4][0][lane] + part[b][4][1][lane] +
               part[b][4][2][lane] + part[b][4][3][lane];
    float swh = part[b][2][0][lane] + part[b][2][1][lane] +
                part[b][2][2][lane] + part[b][2][3][lane];
    float suh = part[b][5][0][lane] + part[b][5][1][lane] +
                part[b][5][2][lane] + part[b][5][3][lane];
    float xc = __shfl(xcv, dd, 64);
    float z2 = sigm(sz + ux0 * xc + tb0);
    float r2g = sigm(sr + ux1 * xc + tb1);
    float hh = ftanh(r2g * swh + ux2 * xc + suh + tb2);
    float Hn = z2 * Hdec_r + (1.f - z2) * hh;

    // ---- role split ----
    if (wid == 0) {
      float xsn = rsum64(xstw_r * Hn);
      if (lane == 0 && t < TT - 1) {
        float xstv = xsn + xstb_r;
        float xcn = mrow[t + 1] * xrow[t + 1] + (1.f - mrow[t + 1]) * xstv;
        unsigned long long pkn =
            (((unsigned long long)(unsigned)(t + 2)) << 32) |
            (unsigned long long)__float_as_uint(xcn);
        __hip_atomic_store(&pf[(size_t)dd * PF_STRIDE + (t + 1)], pkn,
                           __ATOMIC_RELAXED, SC_AGENT);
      }
    } else if (wid == 1) {
      if (t >= 2) {
        float m1 = rmax64(r1v), m2 = rmax64(r2v);
        float e1 = (lane < DD) ? __expf(r1v - m1) : 0.f;
        float e2 = (lane < DD) ? __expf(r2v - m2) : 0.f;
        float s1 = rsum64(e1), s2 = rsum64(e2);
        float r1o = __shfl(r1v, dd, 64);
        float r2o = __shfl(r2v, dd, 64);
        if (lane == 0) {
          float a1 = __expf(r1o - m1) / s1;
          float a2 = __expf(r2o - m2) / s2;
          out[TT * DD * HH + dd * TT + (t - 2)] = a1 * xg_m2 + a2 * xs_m2;
        }
      }
      float xg = whr0_r * hn;
      if (t == 0) {
        xg += wt0_r * h0s_r;
      } else if (t == 1) {
        xg += wt1a_r * h0s_r + wt1b_r * h1;
      } else if (t == 2) {
        xg += wtg0_r * h0s_r + wtg1_r * h2 + wtg2_r * h1;
      } else {
        xg += wtg0_r * h3 + wtg1_r * h2 + wtg2_r * h1;
      }
      float xgt = rsum64(xg);
      float cu = (t == 0) ? cu0_r : (t == 1) ? cu1_r : cu2_r;
      float xsn1 = rsum64(xstw_r * Hn);
      xg_m2 = xg_m1;
      xs_m2 = xs_m1;
      xg_m1 = xgt + whb_r + cu;
      xs_m1 = xst_cur;
      xst_cur = xsn1 + xstb_r;
      h3 = h2;
      h2 = h1;
      h1 = hn;
    } else if (wid == 2) {
      float av = rsum64(wrg_r * hn);
      float bvv = rsum64(wrs_r * Hn);
      if (lane == 0) {
        float s = av + bvv;
        __hip_atomic_store(&ws[O_R + t * 66 + dd], av / s, __ATOMIC_RELAXED,
                           SC_AGENT);
        __hip_atomic_store(&ws[O_R + t * 66 + 33 + dd], bvv / s,
                           __ATOMIC_RELAXED, SC_AGENT);
      }
      asm volatile("s_waitcnt vmcnt(0)" ::: "memory");
    } else {
      out[t * DD * HH + dd * HH + lane] = Hn;
    }
    hprev = hn;
    Hrow = Hn;
    gH_cur = gH_nxt;
    gS_cur = gS_nxt;
  }

  // ---- epilogue: final tag (covers r(TT-2), r(TT-1)); last 2 xpreds ----
  __syncthreads();
  if (wid == 0 && lane == 0) {
    __hip_atomic_store(&pf[(size_t)dd * PF_STRIDE + TT],
                       (((unsigned long long)(unsigned)(TT + 1)) << 32),
                       __ATOMIC_RELAXED, SC_AGENT);
  }
  if (wid == 1) {
    const unsigned tagv = (unsigned)(TT + 1);
    for (;;) {
      unsigned long long pk =
          (lane < NB) ? __hip_atomic_load(&pf[(size_t)lane * PF_STRIDE + TT],
                                          __ATOMIC_RELAXED, SC_AGENT)
                      : (((unsigned long long)tagv) << 32);
      if (__all((int)((unsigned)(pk >> 32) == tagv))) break;
      __builtin_amdgcn_s_sleep(1);
    }
    asm volatile("" ::: "memory");
#pragma unroll 1
    for (int e = 0; e < 2; ++e) {
      const int step = TT - 2 + e;
      float r1v = -INFINITY, r2v = -INFINITY;
      if (lane < DD) {
        r1v = __hip_atomic_load(&ws[O_R + step * 66 + lane], __ATOMIC_RELAXED,
                                SC_AGENT);
        r2v = __hip_atomic_load(&ws[O_R + step * 66 + 33 + lane],
                                __ATOMIC_RELAXED, SC_AGENT);
      }
      float m1 = rmax64(r1v), m2 = rmax64(r2v);
      float e1 = (lane < DD) ? __expf(r1v - m1) : 0.f;
      float e2 = (lane < DD) ? __expf(r2v - m2) : 0.f;
      float s1 = rsum64(e1), s2 = rsum64(e2);
      float r1o = __shfl(r1v, dd, 64);
      float r2o = __shfl(r2v, dd, 64);
      if (lane == 0) {
        float a1 = __expf(r1o - m1) / s1;
        float a2 = __expf(r2o - m2) / s2;
        float xgv = (e == 0) ? xg_m2 : xg_m1;
        float xsv = (e == 0) ? xs_m2 : xs_m1;
        out[TT * DD * HH + dd * TT + step] = a1 * xgv + a2 * xsv;
      }
    }
  }
}

extern "C" void kernel_launch(void* const* d_in, const int* in_sizes, int n_in,
                              void* d_out, int out_size, void* d_ws,
                              size_t ws_size, hipStream_t stream) {
  (void)in_sizes; (void)n_in; (void)out_size; (void)ws_size;
  const float* data   = (const float*)d_in[0];
  const float* h0     = (const float*)d_in[1];
  const float* H0     = (const float*)d_in[2];
  const float* gh_w   = (const float*)d_in[3];
  const float* gh_b   = (const float*)d_in[4];
  const float* gst_w  = (const float*)d_in[5];
  const float* gst_b  = (const float*)d_in[6];
  const float* wih    = (const float*)d_in[7];
  const float* whh    = (const float*)d_in[8];
  const float* bih    = (const float*)d_in[9];
  const float* bhh    = (const float*)d_in[10];
  const float* wu0w   = (const float*)d_in[11];
  const float* wu0b   = (const float*)d_in[12];
  const float* wu1w   = (const float*)d_in[13];
  const float* wu1b   = (const float*)d_in[14];
  const float* wuw    = (const float*)d_in[15];
  const float* wub    = (const float*)d_in[16];
  const float* wh_w   = (const float*)d_in[17];
  const float* wh_b   = (const float*)d_in[18];
  const float* xst_w  = (const float*)d_in[19];
  const float* xst_b  = (const float*)d_in[20];
  const float* wrg_w  = (const float*)d_in[21];
  const float* wrs    = (const float*)d_in[22];
  const float* tWz    = (const float*)d_in[23];
  const float* tUzx   = (const float*)d_in[24];
  const float* tUzh   = (const float*)d_in[25];
  const float* tWr    = (const float*)d_in[26];
  const float* tUrx   = (const float*)d_in[27];
  const float* tUrh   = (const float*)d_in[28];
  const float* tWh    = (const float*)d_in[29];
  const float* tUhx   = (const float*)d_in[30];
  const float* tUhh   = (const float*)d_in[31];
  const float* tbz    = (const float*)d_in[32];
  const float* tbr    = (const float*)d_in[33];
  const float* tbh    = (const float*)d_in[34];

  float* ws = (float*)d_ws;
  unsigned long long* pf = (unsigned long long*)(ws + O_PF);

  hipMemsetAsync(pf, 0, (size_t)NB * PF_STRIDE * 8, stream);
  gmgru_prep<<<(PREP_N + 255) / 256, 256, 0, stream>>>(
      data, gh_w, gh_b, gst_w, gst_b, wih, whh, wu0w, wu0b, wu1w, wu1b, wuw,
      wub, wh_w, ws);
  gmgru_main<<<NB, NT, 0, stream>>>(
      data, h0, H0, bih, bhh, wh_w, wh_b, xst_w, xst_b, wrg_w, wrs, tWz, tUzx,
      tUzh, tWr, tUrx, tUrh, tWh, tUhx, tUhh, tbz, tbr, tbh, ws, pf,
      (float*)d_out);
}